// Round 14
// baseline (97.725 us; speedup 1.0000x reference)
//
#include <hip/hip_runtime.h>

#define ZD   128
#define NP   32
#define SPB  16
#define NBLK (4096 / SPB)
#define NTH  512

typedef __attribute__((ext_vector_type(8))) short bf16x8;   // 8 bf16 = 4 VGPRs
typedef __attribute__((ext_vector_type(4))) float f32x4;

// packed-weight element offsets (bf16 elements), hi only
#define OFF_W0   0
#define OFF_W1   16384
#define OFF_W2   81920
#define OFF_W2T  147456
#define OFF_W1T  212992
#define OFF_W0T  278528

__device__ __forceinline__ float softplus_f(float x) {   // hw exp/log, ~1e-6 abs
    float e = __expf(-fabsf(x));
    return fmaxf(x, 0.0f) + __logf(1.0f + e);
}
__device__ __forceinline__ float sigmoid_f(float x) {
    return 1.0f / (1.0f + __expf(-x));
}
__device__ __forceinline__ unsigned short f2b(float f) {   // RNE float->bf16
    unsigned int u = __float_as_uint(f);
    unsigned int r = (u + 0x7FFFu + ((u >> 16) & 1u)) >> 16;
    return (unsigned short)r;
}
__device__ __forceinline__ double shfld1(double v) {   // lane+1 (guarded by caller)
    return __shfl_down(v, 1, 64);
}

// ---- pack weights (and transposes) into MFMA B-fragment order (bf16 hi) ----
__global__ void prep_pack(const float* __restrict__ W0,
                          const float* __restrict__ W1,
                          const float* __restrict__ W2,
                          short* __restrict__ P) {
    int T = blockIdx.x * 256 + threadIdx.x;
    if (T >= 36864) return;
    const float* src; int base, NT, trans, lu, t = T;
    if (t < 2048)               { src = W0; base = OFF_W0;  NT = 16; trans = 0; lu = t; }
    else if ((t -= 2048) < 8192){ src = W1; base = OFF_W1;  NT = 16; trans = 0; lu = t; }
    else if ((t -= 8192) < 8192){ src = W2; base = OFF_W2;  NT = 16; trans = 0; lu = t; }
    else if ((t -= 8192) < 8192){ src = W2; base = OFF_W2T; NT = 16; trans = 1; lu = t; }
    else if ((t -= 8192) < 8192){ src = W1; base = OFF_W1T; NT = 16; trans = 1; lu = t; }
    else              { t -= 8192; src = W0; base = OFF_W0T; NT = 4; trans = 1; lu = t; }
    int frag = lu >> 6, lane = lu & 63;
    int kb = frag / NT, nt = frag - kb * NT;
    int n  = nt * 16 + (lane & 15);
    int k0 = kb * 32 + ((lane >> 4) << 3);
    int N  = NT * 16;
    bf16x8 hv;
    #pragma unroll
    for (int j = 0; j < 8; ++j) {
        int k = k0 + j;
        float w = trans ? src[n * 256 + k] : src[k * N + n];
        hv[j] = (short)f2b(w);
    }
    ((bf16x8*)(P + base))[lu] = hv;
}

// load B fragments for a pass into registers (global, barrier-independent)
template<int KB, int NT, int TPW>
__device__ __forceinline__ void load_B(const short* __restrict__ BH,
                                       int L, int wvx, bf16x8* dst) {
    #pragma unroll
    for (int kb = 0; kb < KB; ++kb)
        #pragma unroll
        for (int t = 0; t < TPW; ++t)
            dst[kb * TPW + t] = ((const bf16x8*)BH)[(kb * NT + wvx * TPW + t) * 64 + L];
}

// MFMAs for a pass using pre-loaded B registers
template<int KB, int TPW>
__device__ __forceinline__ void mfma_B(const unsigned short (*aH)[264],
                                       int L, int quad,
                                       const bf16x8* fr, f32x4* acc) {
    #pragma unroll
    for (int kb = 0; kb < KB; ++kb) {
        bf16x8 ah = *(const bf16x8*)&aH[L & 15][kb * 32 + quad * 8];
        #pragma unroll
        for (int t = 0; t < TPW; ++t)
            acc[t] = __builtin_amdgcn_mfma_f32_16x16x32_bf16(ah, fr[kb * TPW + t],
                                                             acc[t], 0, 0, 0);
    }
}

__global__ __launch_bounds__(NTH, 2) void chnn_main(
    const float* __restrict__ z, const float* __restrict__ mp,
    const float* __restrict__ B0, const float* __restrict__ B1,
    const float* __restrict__ B2, const float* __restrict__ W3,
    const short* __restrict__ P,
    float* __restrict__ out)
{
    // ping-pong activation buffers: pass i reads buf p, writes buf p^1
    __shared__ __align__(16) unsigned short actH[2][16][264];
    __shared__ __align__(16) float rsh[64][SPB];
    __shared__ __align__(16) float vsh[64][SPB];    // RAW p (not scaled)
    __shared__ __align__(16) float gsh[64][SPB];
    __shared__ double invmd[NP];
    __shared__ float ge[SPB][NP][2], gd[SPB][NP][2];
    __shared__ double Sdd[SPB][NP], Sed[SPB][NP], Ked[SPB][NP];
    __shared__ double b0d[SPB][NP], b1d[SPB][NP];   // become X1, X0 in place
    __shared__ double wfac[SPB][NP], dinv[SPB][NP];

    const int tid  = threadIdx.x;
    const int L    = tid & 63;
    const int wv   = tid >> 6;       // 0..7
    const int quad = L >> 4;
    const long sbase = (long)blockIdx.x * SPB;

    if (tid < NP) invmd[tid] = exp(-(double)mp[tid]);

    // ---- L0 A-operand: each lane fetches its own fragment straight from z ----
    // A[m=L&15][k=kb*32+quad*8+j] = z[(sbase+m)*128 + k]; bit-identical to the
    // old LDS-staged path (same f2b, same MFMA order).
    bf16x8 frZ[2];
    {
        const float* zrow = z + (sbase + (L & 15)) * ZD + quad * 8;
        float4 a0 = *(const float4*)(zrow);
        float4 a1 = *(const float4*)(zrow + 4);
        float4 c0 = *(const float4*)(zrow + 32);
        float4 c1 = *(const float4*)(zrow + 36);
        float va[16] = {a0.x,a0.y,a0.z,a0.w, a1.x,a1.y,a1.z,a1.w,
                        c0.x,c0.y,c0.z,c0.w, c1.x,c1.y,c1.z,c1.w};
        #pragma unroll
        for (int j = 0; j < 8; ++j) { frZ[0][j] = (short)f2b(va[j]);
                                      frZ[1][j] = (short)f2b(va[8 + j]); }
    }

    bf16x8 frA[16], frB[16];
    load_B<2, 16, 2>(P + OFF_W0, L, wv, frA);

    // ---- stage rsh/vsh (fp32) — needed only from constraint phase on; no
    // barrier here: the 6 GEMM barriers below cover these writes. ----
    const float* zb = z + sbase * ZD;
    #pragma unroll
    for (int k = 0; k < 4; ++k) {
        int e = k * NTH + tid;          // 0..2047
        int s = e >> 7, idx = e & 127;
        float val = zb[e];
        if (idx < 64) rsh[idx][s] = val;
        else          vsh[idx - 64][s] = val;
    }

    f32x4 acc[2];
    float p0s[2][4], p1s[2][4];
    const int nbase = wv * 32 + (L & 15);    // 2 tiles/wave, 32 units apart

    // ---- L0: A from registers (frZ), B=frA; writes buf1; prefetch W1 ----
    load_B<8, 16, 2>(P + OFF_W1, L, wv, frB);
    #pragma unroll
    for (int t = 0; t < 2; ++t) {
        float bb = B0[nbase + t * 16];
        acc[t] = (f32x4){bb, bb, bb, bb};
    }
    #pragma unroll
    for (int kb = 0; kb < 2; ++kb)
        #pragma unroll
        for (int t = 0; t < 2; ++t)
            acc[t] = __builtin_amdgcn_mfma_f32_16x16x32_bf16(frZ[kb], frA[kb * 2 + t],
                                                             acc[t], 0, 0, 0);
    #pragma unroll
    for (int t = 0; t < 2; ++t) {
        int n = nbase + t * 16;
        #pragma unroll
        for (int r = 0; r < 4; ++r) {
            p0s[t][r] = acc[t][r];
            actH[1][quad * 4 + r][n] = f2b(softplus_f(acc[t][r]));
        }
    }
    __syncthreads();

    // ---- L1: reads buf1 (frB), writes buf0; prefetch W2 -> frA ----
    load_B<8, 16, 2>(P + OFF_W2, L, wv, frA);
    #pragma unroll
    for (int t = 0; t < 2; ++t) {
        float bb = B1[nbase + t * 16];
        acc[t] = (f32x4){bb, bb, bb, bb};
    }
    mfma_B<8, 2>(actH[1], L, quad, frB, acc);
    #pragma unroll
    for (int t = 0; t < 2; ++t) {
        int n = nbase + t * 16;
        #pragma unroll
        for (int r = 0; r < 4; ++r) {
            p1s[t][r] = acc[t][r];
            actH[0][quad * 4 + r][n] = f2b(softplus_f(acc[t][r]));
        }
    }
    __syncthreads();

    // ---- L2 + head: reads buf0 (frA), writes buf1; prefetch W2T -> frB ----
    load_B<8, 16, 2>(P + OFF_W2T, L, wv, frB);
    #pragma unroll
    for (int t = 0; t < 2; ++t) {
        float bb = B2[nbase + t * 16];
        acc[t] = (f32x4){bb, bb, bb, bb};
    }
    mfma_B<8, 2>(actH[0], L, quad, frA, acc);
    #pragma unroll
    for (int t = 0; t < 2; ++t) {
        int n = nbase + t * 16;
        float w3 = W3[n];
        #pragma unroll
        for (int r = 0; r < 4; ++r)
            actH[1][quad * 4 + r][n] = f2b(w3 * sigmoid_f(acc[t][r]));
    }
    __syncthreads();

    // ---- dB = sigmoid(p1)*(dA @ W2^T): reads buf1 (frB), writes buf0 ----
    load_B<8, 16, 2>(P + OFF_W1T, L, wv, frA);
    #pragma unroll
    for (int t = 0; t < 2; ++t) acc[t] = (f32x4){0.f, 0.f, 0.f, 0.f};
    mfma_B<8, 2>(actH[1], L, quad, frB, acc);
    #pragma unroll
    for (int t = 0; t < 2; ++t) {
        int n = nbase + t * 16;
        #pragma unroll
        for (int r = 0; r < 4; ++r)
            actH[0][quad * 4 + r][n] = f2b(acc[t][r] * sigmoid_f(p1s[t][r]));
    }
    __syncthreads();

    // ---- d0 = sigmoid(p0)*(dB @ W1^T): reads buf0 (frA), writes buf1 ----
    if (wv < 4) load_B<8, 4, 1>(P + OFF_W0T, L, wv, frB);
    #pragma unroll
    for (int t = 0; t < 2; ++t) acc[t] = (f32x4){0.f, 0.f, 0.f, 0.f};
    mfma_B<8, 2>(actH[0], L, quad, frA, acc);
    #pragma unroll
    for (int t = 0; t < 2; ++t) {
        int n = nbase + t * 16;
        #pragma unroll
        for (int r = 0; r < 4; ++r)
            actH[1][quad * 4 + r][n] = f2b(acc[t][r] * sigmoid_f(p0s[t][r]));
    }
    __syncthreads();

    // ---- g = d0 @ W0^T (N=64): waves 0..3, reads buf1 (frB) ----
    if (wv < 4) {
        acc[0] = (f32x4){0.f, 0.f, 0.f, 0.f};
        mfma_B<8, 1>(actH[1], L, quad, frB, acc);
        int i = wv * 16 + (L & 15);
        #pragma unroll
        for (int r = 0; r < 4; ++r)
            gsh[i][quad * 4 + r] = acc[0][r];
    }
    __syncthreads();

    // ---- constraint assembly (fp64), single phase, shuffles for c+1 ----
    {
        const int c = tid & 31;
        const int s = tid >> 5;          // 0..15
        double gx, gy, gdx, gdy;
        if (c == 0) {
            double v0x = invmd[0] * (double)vsh[0][s];
            double v0y = invmd[0] * (double)vsh[1][s];
            gx = 2.0 * (double)rsh[0][s]; gy = 2.0 * (double)rsh[1][s];
            gdx = 2.0 * v0x; gdy = 2.0 * v0y;
            Sdd[s][0] = invmd[0] * (gx * gx + gy * gy);
            b0d[s][0] = gx * v0x + gy * v0y;
            b1d[s][0] = gdx * v0x + gdy * v0y
                      - invmd[0] * (gx * (double)gsh[0][s] + gy * (double)gsh[1][s]);
        } else {
            int aa = 2 * (c - 1), b = 2 * c;
            double vax = invmd[c - 1] * (double)vsh[aa][s];
            double vay = invmd[c - 1] * (double)vsh[aa + 1][s];
            double vbx = invmd[c] * (double)vsh[b][s];
            double vby = invmd[c] * (double)vsh[b + 1][s];
            double dvx = vax - vbx, dvy = vay - vby;
            gx = 2.0 * ((double)rsh[aa][s] - (double)rsh[b][s]);
            gy = 2.0 * ((double)rsh[aa + 1][s] - (double)rsh[b + 1][s]);
            gdx = 2.0 * dvx; gdy = 2.0 * dvy;
            Sdd[s][c] = (invmd[c - 1] + invmd[c]) * (gx * gx + gy * gy);
            b0d[s][c] = gx * dvx + gy * dvy;
            double mgx = invmd[c - 1] * (double)gsh[aa][s]     - invmd[c] * (double)gsh[b][s];
            double mgy = invmd[c - 1] * (double)gsh[aa + 1][s] - invmd[c] * (double)gsh[b + 1][s];
            b1d[s][c] = gdx * dvx + gdy * dvy - (gx * mgx + gy * mgy);
        }
        ge[s][c][0] = (float)gx;  ge[s][c][1] = (float)gy;
        gd[s][c][0] = (float)gdx; gd[s][c][1] = (float)gdy;
        // neighbor (c+1) via lane+1 shuffle — same wave, same sample when c<31
        double g1x = shfld1(gx),  g1y = shfld1(gy);
        double q1x = shfld1(gdx), q1y = shfld1(gdy);
        if (c < 31) {
            if (c == 0) {
                Sed[s][0] = invmd[0] * (gx * g1x + gy * g1y);
                Ked[s][0] = invmd[0] * ((gdx * g1x + gdy * g1y) - (gx * q1x + gy * q1y));
            } else {
                Sed[s][c] = -invmd[c] * (gx * g1x + gy * g1y);
                Ked[s][c] =  invmd[c] * ((gx * q1x + gy * q1y) - (gdx * g1x + gdy * g1y));
            }
        }
    }
    __syncthreads();

    // ---- fp64 Thomas x2 + fused rhs2, all in wave 0 (no inner barriers) ----
    if (tid < SPB) {
        int s = tid;
        // factor + solve S X1 = b0 (in place in b0d)
        double d = Sdd[s][0];
        if (d == 0.0) d = 1e-300;
        dinv[s][0] = 1.0 / d;
        double y = b0d[s][0];
        for (int c = 1; c < NP; ++c) {
            double e = Sed[s][c - 1];
            double w = e * dinv[s][c - 1];
            wfac[s][c - 1] = w;
            d = Sdd[s][c] - w * e;
            if (d == 0.0) d = 1e-300;
            dinv[s][c] = 1.0 / d;
            y = b0d[s][c] - w * y;
            b0d[s][c] = y;
        }
        double x = b0d[s][31] * dinv[s][31];
        b0d[s][31] = x;
        for (int c = 30; c >= 0; --c) {
            x = (b0d[s][c] - Sed[s][c] * x) * dinv[s][c];
            b0d[s][c] = x;
        }
        // second solve S X0 = K X1 - b1, rhs computed on the fly (X1 = b0d)
        y = Ked[s][0] * b0d[s][1] - b1d[s][0];
        b1d[s][0] = y;
        for (int c = 1; c < NP; ++c) {
            double kx = -Ked[s][c - 1] * b0d[s][c - 1];
            if (c < 31) kx += Ked[s][c] * b0d[s][c + 1];
            y = (kx - b1d[s][c]) - wfac[s][c - 1] * y;
            b1d[s][c] = y;
        }
        x = b1d[s][31] * dinv[s][31];
        b1d[s][31] = x;
        for (int c = 30; c >= 0; --c) {
            x = (b1d[s][c] - Sed[s][c] * x) * dinv[s][c];
            b1d[s][c] = x;
        }
    }
    __syncthreads();

    // ---- output: [invm*(p - G X1) ; -g + G X0 + Gdot X1]  (X1=b0d, X0=b1d) ----
    float* ob = out + sbase * ZD;
    #pragma unroll
    for (int k = 0; k < 4; ++k) {
        int e = k * NTH + tid;
        int s = e >> 7, idx = e & 127;
        int j = idx & 63;
        int n = j >> 1, d = j & 1;
        float res;
        if (idx < 64) {
            double Gx1 = (n == 0) ? (double)ge[s][0][d] * b0d[s][0]
                                  : -(double)ge[s][n][d] * b0d[s][n];
            if (n < 31) Gx1 += (double)ge[s][n + 1][d] * b0d[s][n + 1];
            res = (float)(invmd[n] * ((double)vsh[j][s] - Gx1));
        } else {
            double Gx0 = (n == 0) ? (double)ge[s][0][d] * b1d[s][0]
                                  : -(double)ge[s][n][d] * b1d[s][n];
            if (n < 31) Gx0 += (double)ge[s][n + 1][d] * b1d[s][n + 1];
            double Gd1 = (n == 0) ? (double)gd[s][0][d] * b0d[s][0]
                                  : -(double)gd[s][n][d] * b0d[s][n];
            if (n < 31) Gd1 += (double)gd[s][n + 1][d] * b0d[s][n + 1];
            res = (float)(-(double)gsh[j][s] + Gx0 + Gd1);
        }
        ob[e] = res;
    }
}

extern "C" void kernel_launch(void* const* d_in, const int* in_sizes, int n_in,
                              void* d_out, int out_size, void* d_ws, size_t ws_size,
                              hipStream_t stream) {
    const float* z  = (const float*)d_in[1];
    const float* mp = (const float*)d_in[2];
    const float* W0 = (const float*)d_in[3];
    const float* B0 = (const float*)d_in[4];
    const float* W1 = (const float*)d_in[5];
    const float* B1 = (const float*)d_in[6];
    const float* W2 = (const float*)d_in[7];
    const float* B2 = (const float*)d_in[8];
    const float* W3 = (const float*)d_in[9];

    short* P = (short*)d_ws;   // 294912 bf16 elements = 576 KB packed weights

    prep_pack<<<144, 256, 0, stream>>>(W0, W1, W2, P);
    chnn_main<<<NBLK, NTH, 0, stream>>>(z, mp, B0, B1, B2, W3, P, (float*)d_out);
}

// Round 15
// 94.555 us; speedup vs baseline: 1.0335x; 1.0335x over previous
//
#include <hip/hip_runtime.h>

#define ZD   128
#define NP   32
#define SPB  16
#define NBLK (4096 / SPB)
#define NTH  512

typedef __attribute__((ext_vector_type(8))) short bf16x8;   // 8 bf16 = 4 VGPRs
typedef __attribute__((ext_vector_type(4))) float f32x4;

// packed-weight element offsets (bf16 elements), hi only
#define OFF_W0   0
#define OFF_W1   16384
#define OFF_W2   81920
#define OFF_W2T  147456
#define OFF_W1T  212992
#define OFF_W0T  278528

__device__ __forceinline__ float softplus_f(float x) {   // hw exp/log, ~1e-6 abs
    float e = __expf(-fabsf(x));
    return fmaxf(x, 0.0f) + __logf(1.0f + e);
}
__device__ __forceinline__ float sigmoid_f(float x) {
    return 1.0f / (1.0f + __expf(-x));
}
__device__ __forceinline__ unsigned short f2b(float f) {   // RNE float->bf16
    unsigned int u = __float_as_uint(f);
    unsigned int r = (u + 0x7FFFu + ((u >> 16) & 1u)) >> 16;
    return (unsigned short)r;
}

// ---- pack weights (and transposes) into MFMA B-fragment order (bf16 hi) ----
__global__ void prep_pack(const float* __restrict__ W0,
                          const float* __restrict__ W1,
                          const float* __restrict__ W2,
                          short* __restrict__ P) {
    int T = blockIdx.x * 256 + threadIdx.x;
    if (T >= 36864) return;
    const float* src; int base, NT, trans, lu, t = T;
    if (t < 2048)               { src = W0; base = OFF_W0;  NT = 16; trans = 0; lu = t; }
    else if ((t -= 2048) < 8192){ src = W1; base = OFF_W1;  NT = 16; trans = 0; lu = t; }
    else if ((t -= 8192) < 8192){ src = W2; base = OFF_W2;  NT = 16; trans = 0; lu = t; }
    else if ((t -= 8192) < 8192){ src = W2; base = OFF_W2T; NT = 16; trans = 1; lu = t; }
    else if ((t -= 8192) < 8192){ src = W1; base = OFF_W1T; NT = 16; trans = 1; lu = t; }
    else              { t -= 8192; src = W0; base = OFF_W0T; NT = 4; trans = 1; lu = t; }
    int frag = lu >> 6, lane = lu & 63;
    int kb = frag / NT, nt = frag - kb * NT;
    int n  = nt * 16 + (lane & 15);
    int k0 = kb * 32 + ((lane >> 4) << 3);
    int N  = NT * 16;
    bf16x8 hv;
    #pragma unroll
    for (int j = 0; j < 8; ++j) {
        int k = k0 + j;
        float w = trans ? src[n * 256 + k] : src[k * N + n];
        hv[j] = (short)f2b(w);
    }
    ((bf16x8*)(P + base))[lu] = hv;
}

// load B fragments for a pass into registers (global, barrier-independent)
template<int KB, int NT, int TPW>
__device__ __forceinline__ void load_B(const short* __restrict__ BH,
                                       int L, int wvx, bf16x8* dst) {
    #pragma unroll
    for (int kb = 0; kb < KB; ++kb)
        #pragma unroll
        for (int t = 0; t < TPW; ++t)
            dst[kb * TPW + t] = ((const bf16x8*)BH)[(kb * NT + wvx * TPW + t) * 64 + L];
}

// MFMAs for a pass using pre-loaded B registers
template<int KB, int TPW>
__device__ __forceinline__ void mfma_B(const unsigned short (*aH)[264],
                                       int L, int quad,
                                       const bf16x8* fr, f32x4* acc) {
    #pragma unroll
    for (int kb = 0; kb < KB; ++kb) {
        bf16x8 ah = *(const bf16x8*)&aH[L & 15][kb * 32 + quad * 8];
        #pragma unroll
        for (int t = 0; t < TPW; ++t)
            acc[t] = __builtin_amdgcn_mfma_f32_16x16x32_bf16(ah, fr[kb * TPW + t],
                                                             acc[t], 0, 0, 0);
    }
}

__global__ __launch_bounds__(NTH, 2) void chnn_main(
    const float* __restrict__ z, const float* __restrict__ mp,
    const float* __restrict__ B0, const float* __restrict__ B1,
    const float* __restrict__ B2, const float* __restrict__ W3,
    const short* __restrict__ P,
    float* __restrict__ out)
{
    // ping-pong activation buffers: pass i reads buf p, writes buf p^1
    __shared__ __align__(16) unsigned short actH[2][16][264];
    __shared__ __align__(16) float rsh[64][SPB];
    __shared__ __align__(16) float vsh[64][SPB];
    __shared__ __align__(16) float gsh[64][SPB];
    __shared__ float invm[NP];
    __shared__ double invmd[NP];
    __shared__ float ge[SPB][NP][2], gd[SPB][NP][2];
    __shared__ double Sdd[SPB][NP], Sed[SPB][NP], Ked[SPB][NP];
    __shared__ double b0d[SPB][NP], b1d[SPB][NP];   // become X1, X0 in place
    __shared__ double wfac[SPB][NP], dinv[SPB][NP];

    const int tid  = threadIdx.x;
    const int L    = tid & 63;
    const int wv   = tid >> 6;       // 0..7
    const int quad = L >> 4;
    const long sbase = (long)blockIdx.x * SPB;

    if (tid < NP) {
        double e = exp(-(double)mp[tid]);
        invmd[tid] = e;
        invm[tid] = (float)e;
    }

    bf16x8 frA[16], frB[16];
    // prefetch L0 weights immediately (independent of staging)
    load_B<2, 16, 2>(P + OFF_W0, L, wv, frA);

    // ---- stage z: 16 samples x 128; r bf16 into buf 0 ----
    const float* zb = z + sbase * ZD;
    #pragma unroll
    for (int k = 0; k < 4; ++k) {
        int e = k * NTH + tid;          // 0..2047
        int s = e >> 7, idx = e & 127;
        float val = zb[e];
        if (idx < 64) {
            rsh[idx][s] = val;
            actH[0][s][idx] = f2b(val);
        } else {
            vsh[idx - 64][s] = val;
        }
    }
    __syncthreads();
    {   // p -> v = inv_m * p  (flat e = j*16+s, particle n = e>>5)
        float* pv = &vsh[0][0];
        #pragma unroll
        for (int k = 0; k < 2; ++k) {
            int e = k * NTH + tid;
            pv[e] *= invm[e >> 5];
        }
    }
    __syncthreads();

    f32x4 acc[2];
    float p0s[2][4], p1s[2][4];
    const int nbase = wv * 32 + (L & 15);    // 2 tiles/wave, 32 units apart

    // ---- L0: reads buf0 (frA), writes buf1; prefetch W1 -> frB ----
    load_B<8, 16, 2>(P + OFF_W1, L, wv, frB);
    #pragma unroll
    for (int t = 0; t < 2; ++t) {
        float bb = B0[nbase + t * 16];
        acc[t] = (f32x4){bb, bb, bb, bb};
    }
    mfma_B<2, 2>(actH[0], L, quad, frA, acc);
    #pragma unroll
    for (int t = 0; t < 2; ++t) {
        int n = nbase + t * 16;
        #pragma unroll
        for (int r = 0; r < 4; ++r) {
            p0s[t][r] = acc[t][r];
            actH[1][quad * 4 + r][n] = f2b(softplus_f(acc[t][r]));
        }
    }
    __syncthreads();

    // ---- L1: reads buf1 (frB), writes buf0; prefetch W2 -> frA ----
    load_B<8, 16, 2>(P + OFF_W2, L, wv, frA);
    #pragma unroll
    for (int t = 0; t < 2; ++t) {
        float bb = B1[nbase + t * 16];
        acc[t] = (f32x4){bb, bb, bb, bb};
    }
    mfma_B<8, 2>(actH[1], L, quad, frB, acc);
    #pragma unroll
    for (int t = 0; t < 2; ++t) {
        int n = nbase + t * 16;
        #pragma unroll
        for (int r = 0; r < 4; ++r) {
            p1s[t][r] = acc[t][r];
            actH[0][quad * 4 + r][n] = f2b(softplus_f(acc[t][r]));
        }
    }
    __syncthreads();

    // ---- L2 + head: reads buf0 (frA), writes buf1; prefetch W2T -> frB ----
    load_B<8, 16, 2>(P + OFF_W2T, L, wv, frB);
    #pragma unroll
    for (int t = 0; t < 2; ++t) {
        float bb = B2[nbase + t * 16];
        acc[t] = (f32x4){bb, bb, bb, bb};
    }
    mfma_B<8, 2>(actH[0], L, quad, frA, acc);
    #pragma unroll
    for (int t = 0; t < 2; ++t) {
        int n = nbase + t * 16;
        float w3 = W3[n];
        #pragma unroll
        for (int r = 0; r < 4; ++r)
            actH[1][quad * 4 + r][n] = f2b(w3 * sigmoid_f(acc[t][r]));
    }
    __syncthreads();

    // ---- dB = sigmoid(p1)*(dA @ W2^T): reads buf1 (frB), writes buf0 ----
    load_B<8, 16, 2>(P + OFF_W1T, L, wv, frA);
    #pragma unroll
    for (int t = 0; t < 2; ++t) acc[t] = (f32x4){0.f, 0.f, 0.f, 0.f};
    mfma_B<8, 2>(actH[1], L, quad, frB, acc);
    #pragma unroll
    for (int t = 0; t < 2; ++t) {
        int n = nbase + t * 16;
        #pragma unroll
        for (int r = 0; r < 4; ++r)
            actH[0][quad * 4 + r][n] = f2b(acc[t][r] * sigmoid_f(p1s[t][r]));
    }
    __syncthreads();

    // ---- d0 = sigmoid(p0)*(dB @ W1^T): reads buf0 (frA), writes buf1 ----
    if (wv < 4) load_B<8, 4, 1>(P + OFF_W0T, L, wv, frB);
    #pragma unroll
    for (int t = 0; t < 2; ++t) acc[t] = (f32x4){0.f, 0.f, 0.f, 0.f};
    mfma_B<8, 2>(actH[0], L, quad, frA, acc);
    #pragma unroll
    for (int t = 0; t < 2; ++t) {
        int n = nbase + t * 16;
        #pragma unroll
        for (int r = 0; r < 4; ++r)
            actH[1][quad * 4 + r][n] = f2b(acc[t][r] * sigmoid_f(p0s[t][r]));
    }
    __syncthreads();

    // ---- g = d0 @ W0^T (N=64): waves 0..3, reads buf1 (frB) ----
    if (wv < 4) {
        acc[0] = (f32x4){0.f, 0.f, 0.f, 0.f};
        mfma_B<8, 1>(actH[1], L, quad, frB, acc);
        int i = wv * 16 + (L & 15);
        #pragma unroll
        for (int r = 0; r < 4; ++r)
            gsh[i][quad * 4 + r] = acc[0][r];
    }
    __syncthreads();

    // ---- constraint assembly (fp64): 512 thr = 16 samples x 32 constraints ----
    {
        const int c = tid & 31;
        const int s = tid >> 5;          // 0..15
        double gx, gy, gdx, gdy;
        if (c == 0) {
            double r0x = rsh[0][s], r0y = rsh[1][s];
            double v0x = vsh[0][s], v0y = vsh[1][s];
            gx = 2.0 * r0x; gy = 2.0 * r0y; gdx = 2.0 * v0x; gdy = 2.0 * v0y;
            Sdd[s][0] = invmd[0] * (gx * gx + gy * gy);
            b0d[s][0] = gx * v0x + gy * v0y;
            b1d[s][0] = gdx * v0x + gdy * v0y
                      - invmd[0] * (gx * (double)gsh[0][s] + gy * (double)gsh[1][s]);
        } else {
            int aa = 2 * (c - 1), b = 2 * c;
            double dvx = (double)vsh[aa][s] - (double)vsh[b][s];
            double dvy = (double)vsh[aa + 1][s] - (double)vsh[b + 1][s];
            gx = 2.0 * ((double)rsh[aa][s] - (double)rsh[b][s]);
            gy = 2.0 * ((double)rsh[aa + 1][s] - (double)rsh[b + 1][s]);
            gdx = 2.0 * dvx; gdy = 2.0 * dvy;
            Sdd[s][c] = (invmd[c - 1] + invmd[c]) * (gx * gx + gy * gy);
            b0d[s][c] = gx * dvx + gy * dvy;
            double mgx = invmd[c - 1] * (double)gsh[aa][s]     - invmd[c] * (double)gsh[b][s];
            double mgy = invmd[c - 1] * (double)gsh[aa + 1][s] - invmd[c] * (double)gsh[b + 1][s];
            b1d[s][c] = gdx * dvx + gdy * dvy - (gx * mgx + gy * mgy);
        }
        ge[s][c][0] = (float)gx;  ge[s][c][1] = (float)gy;
        gd[s][c][0] = (float)gdx; gd[s][c][1] = (float)gdy;
        __syncthreads();
        if (c < 31) {
            double g1x = ge[s][c + 1][0], g1y = ge[s][c + 1][1];
            double q1x = gd[s][c + 1][0], q1y = gd[s][c + 1][1];
            if (c == 0) {
                Sed[s][0] = invmd[0] * (gx * g1x + gy * g1y);
                Ked[s][0] = invmd[0] * ((gdx * g1x + gdy * g1y) - (gx * q1x + gy * q1y));
            } else {
                Sed[s][c] = -invmd[c] * (gx * g1x + gy * g1y);
                Ked[s][c] =  invmd[c] * ((gx * q1x + gy * q1y) - (gdx * g1x + gdy * g1y));
            }
        }
    }
    __syncthreads();

    // ---- fp64 Thomas: factor S, solve S X1 = b0 (in place in b0d) ----
    if (tid < SPB) {
        int s = tid;
        double d = Sdd[s][0];
        if (d == 0.0) d = 1e-300;
        dinv[s][0] = 1.0 / d;
        double y = b0d[s][0];
        for (int c = 1; c < NP; ++c) {
            double e = Sed[s][c - 1];
            double w = e * dinv[s][c - 1];
            wfac[s][c - 1] = w;
            d = Sdd[s][c] - w * e;
            if (d == 0.0) d = 1e-300;
            dinv[s][c] = 1.0 / d;
            y = b0d[s][c] - w * y;
            b0d[s][c] = y;
        }
        double x = b0d[s][31] * dinv[s][31];
        b0d[s][31] = x;
        for (int c = 30; c >= 0; --c) {
            x = (b0d[s][c] - Sed[s][c] * x) * dinv[s][c];
            b0d[s][c] = x;
        }
    }
    __syncthreads();

    // ---- rhs2 = K X1 - b1 (in place in b1d) ----
    {
        int c = tid & 31, s = tid >> 5;
        double kx = 0.0;
        if (c < 31) kx += Ked[s][c] * b0d[s][c + 1];
        if (c > 0)  kx -= Ked[s][c - 1] * b0d[s][c - 1];
        b1d[s][c] = kx - b1d[s][c];
    }
    __syncthreads();

    // ---- solve S X0 = rhs2 with stored factors (in place in b1d) ----
    if (tid < SPB) {
        int s = tid;
        double y = b1d[s][0];
        for (int c = 1; c < NP; ++c) {
            y = b1d[s][c] - wfac[s][c - 1] * y;
            b1d[s][c] = y;
        }
        double x = b1d[s][31] * dinv[s][31];
        b1d[s][31] = x;
        for (int c = 30; c >= 0; --c) {
            x = (b1d[s][c] - Sed[s][c] * x) * dinv[s][c];
            b1d[s][c] = x;
        }
    }
    __syncthreads();

    // ---- output: [v - M^-1 G X1 ; -g + G X0 + Gdot X1]   (X1=b0d, X0=b1d) ----
    float* ob = out + sbase * ZD;
    #pragma unroll
    for (int k = 0; k < 4; ++k) {
        int e = k * NTH + tid;
        int s = e >> 7, idx = e & 127;
        int j = idx & 63;
        int n = j >> 1, d = j & 1;
        float res;
        if (idx < 64) {
            double Gx1 = (n == 0) ? (double)ge[s][0][d] * b0d[s][0]
                                  : -(double)ge[s][n][d] * b0d[s][n];
            if (n < 31) Gx1 += (double)ge[s][n + 1][d] * b0d[s][n + 1];
            res = (float)((double)vsh[j][s] - invmd[n] * Gx1);
        } else {
            double Gx0 = (n == 0) ? (double)ge[s][0][d] * b1d[s][0]
                                  : -(double)ge[s][n][d] * b1d[s][n];
            if (n < 31) Gx0 += (double)ge[s][n + 1][d] * b1d[s][n + 1];
            double Gd1 = (n == 0) ? (double)gd[s][0][d] * b0d[s][0]
                                  : -(double)gd[s][n][d] * b0d[s][n];
            if (n < 31) Gd1 += (double)gd[s][n + 1][d] * b0d[s][n + 1];
            res = (float)(-(double)gsh[j][s] + Gx0 + Gd1);
        }
        ob[e] = res;
    }
}

extern "C" void kernel_launch(void* const* d_in, const int* in_sizes, int n_in,
                              void* d_out, int out_size, void* d_ws, size_t ws_size,
                              hipStream_t stream) {
    const float* z  = (const float*)d_in[1];
    const float* mp = (const float*)d_in[2];
    const float* W0 = (const float*)d_in[3];
    const float* B0 = (const float*)d_in[4];
    const float* W1 = (const float*)d_in[5];
    const float* B1 = (const float*)d_in[6];
    const float* W2 = (const float*)d_in[7];
    const float* B2 = (const float*)d_in[8];
    const float* W3 = (const float*)d_in[9];

    short* P = (short*)d_ws;   // 294912 bf16 elements = 576 KB packed weights

    prep_pack<<<144, 256, 0, stream>>>(W0, W1, W2, P);
    chnn_main<<<NBLK, NTH, 0, stream>>>(z, mp, B0, B1, B2, W3, P, (float*)d_out);
}